// Round 5
// baseline (297.017 us; speedup 1.0000x reference)
//
#include <hip/hip_runtime.h>
#include <cstdint>

// MHA fused: qh = (q@Wq^T)*0.125*log2e, kh = k@Wk^T (+khT transposed copy),
// flash-causal-attn(qh,kh,V=kh) with deferred-normalization softmax, out = ao@Wo^T.
// All stages: double-buffered LDS staging via global_load_lds (DMA for tile t+1
// issued before compute of tile t; ONE barrier per iter).
// Flash uses 512-thread blocks (8 waves) to hold 16 waves/CU at 2 blocks/CU.
// B=4 T=2048 E=1024 H=16 D=64. v input (d_in[2]) DEAD (share_kv=True).

typedef unsigned short u16;
typedef __attribute__((ext_vector_type(8))) short short8;
typedef __attribute__((ext_vector_type(4))) float f32x4;
typedef __attribute__((ext_vector_type(4))) unsigned short u16x4;

__device__ __forceinline__ u16 f2bf(float x) {
  unsigned int u = __float_as_uint(x);
  u += 0x7fffu + ((u >> 16) & 1u);   // RNE
  return (u16)(u >> 16);
}

__device__ __forceinline__ float fexp2(float x) {
#if __has_builtin(__builtin_amdgcn_exp2f)
  return __builtin_amdgcn_exp2f(x);
#else
  return __expf(x * 0.69314718056f);
#endif
}

__device__ __forceinline__ float frcp(float x) {
#if __has_builtin(__builtin_amdgcn_rcpf)
  return __builtin_amdgcn_rcpf(x);
#else
  return 1.0f / x;
#endif
}

__device__ __forceinline__ void load16_to_lds(const void* g, void* lds_base_uniform) {
  // HW writes LDS at wave-uniform base + lane*16; g is per-lane.
  __builtin_amdgcn_global_load_lds(
      (const __attribute__((address_space(1))) void*)g,
      (__attribute__((address_space(3))) void*)lds_base_uniform,
      16, 0, 0);
}

// ---------------- casts (merged) ----------------
__global__ void cast_qk(const float* __restrict__ q, const float* __restrict__ k,
                        u16* __restrict__ qb, u16* __restrict__ kb) {
  const float* s = blockIdx.y ? k : q;
  u16* d = blockIdx.y ? kb : qb;
  int i = blockIdx.x * 256 + threadIdx.x;
  float4 f = ((const float4*)s)[i];
  uint2 p;
  p.x = (unsigned int)f2bf(f.x) | ((unsigned int)f2bf(f.y) << 16);
  p.y = (unsigned int)f2bf(f.z) | ((unsigned int)f2bf(f.w) << 16);
  ((uint2*)d)[i] = p;
}

__global__ void cast_w(const float* __restrict__ w0, const float* __restrict__ w1,
                       const float* __restrict__ w2, u16* __restrict__ d0,
                       u16* __restrict__ d1, u16* __restrict__ d2) {
  const float* s = blockIdx.y == 0 ? w0 : (blockIdx.y == 1 ? w1 : w2);
  u16* d = blockIdx.y == 0 ? d0 : (blockIdx.y == 1 ? d1 : d2);
  int i = blockIdx.x * 256 + threadIdx.x;
  float4 f = ((const float4*)s)[i];
  uint2 p;
  p.x = (unsigned int)f2bf(f.x) | ((unsigned int)f2bf(f.y) << 16);
  p.y = (unsigned int)f2bf(f.z) | ((unsigned int)f2bf(f.w) << 16);
  ((uint2*)d)[i] = p;
}

// ---------------- GEMM mainloop: C128x128 = A(128xK) * W(128xK)^T ----------------
// BK=32, double-buffered LDS (2x8KB per operand = 32KB total -> >=3 blocks/CU).
// XOR-swizzled 16B chunks: phys chunk (row*4 + c4) holds logical cols
// ((c4 ^ (row&3))*8 ..+7). K=1024 fixed. 4 waves, 2x2 wave grid, 4x4 frags/wave.
// One barrier per iter: prefetch t+1 -> compute t -> barrier.
__device__ __forceinline__ void gemm_mainloop(
    const u16* __restrict__ A, const u16* __restrict__ W,
    u16* As, u16* Bs, int tm, int tn, int w, int lane, f32x4 acc[4][4])
{
  const int K = 1024;
  const int wr = (w >> 1) * 64, wc = (w & 1) * 64;
  const int l15 = lane & 15, l4 = lane >> 4;

#define STAGE(k0, bf)                                                              \
  {                                                                                \
    _Pragma("unroll")                                                              \
    for (int c = 0; c < 2; ++c) {                                                  \
      int ch = (w * 2 + c) * 64 + lane;        /* phys 16B-chunk 0..511 */         \
      int row = ch >> 2;                                                           \
      int col = ((ch & 3) ^ (row & 3)) * 8;                                        \
      load16_to_lds(A + (size_t)(tm + row) * K + (k0) + col,                       \
                    (char*)(As + (bf) * 4096) + (w * 2 + c) * 1024);               \
      load16_to_lds(W + (size_t)(tn + row) * K + (k0) + col,                       \
                    (char*)(Bs + (bf) * 4096) + (w * 2 + c) * 1024);               \
    }                                                                              \
  }

  STAGE(0, 0);
  __syncthreads();
  for (int t = 0; t < 32; ++t) {
    if (t < 31) STAGE((t + 1) << 5, (t + 1) & 1);
    const u16* Ac = As + (t & 1) * 4096;
    const u16* Bc = Bs + (t & 1) * 4096;
    short8 af[4], bfr[4];
#pragma unroll
    for (int tt = 0; tt < 4; ++tt) {
      int ra = wr + tt * 16 + l15, rb = wc + tt * 16 + l15;
      af[tt]  = *(const short8*)&Ac[ra * 32 + ((l4 ^ (ra & 3)) * 8)];
      bfr[tt] = *(const short8*)&Bc[rb * 32 + ((l4 ^ (rb & 3)) * 8)];
    }
#pragma unroll
    for (int rt = 0; rt < 4; ++rt)
#pragma unroll
      for (int nt = 0; nt < 4; ++nt)
        acc[rt][nt] = __builtin_amdgcn_mfma_f32_16x16x32_bf16(af[rt], bfr[nt], acc[rt][nt], 0, 0, 0);
    __syncthreads();   // drains frag ds_reads (all waves) + next buffer's DMA
  }
#undef STAGE
}

// ---------------- Q + K projections, one dispatch (grid.z selects) ----------------
__global__ __launch_bounds__(256) void gemm_qk(
    const u16* __restrict__ qb, const u16* __restrict__ Wq,
    const u16* __restrict__ kb, const u16* __restrict__ Wk,
    u16* __restrict__ qh, u16* __restrict__ kh, u16* __restrict__ khT)
{
  __shared__ __align__(16) u16 As[2 * 4096];
  __shared__ __align__(16) u16 Bs[2 * 4096];
  const int z = blockIdx.z;
  const u16* A = z ? kb : qb;
  const u16* W = z ? Wk : Wq;
  const int tid = threadIdx.x, w = tid >> 6, lane = tid & 63;
  const int l15 = lane & 15, l4 = lane >> 4;
  const int tm = blockIdx.y * 128, tn = blockIdx.x * 128;
  const int wr = (w >> 1) * 64, wc = (w & 1) * 64;
  const int N = 1024;

  f32x4 zero4 = {0.f, 0.f, 0.f, 0.f};
  f32x4 acc[4][4];
  for (int i = 0; i < 4; ++i)
    for (int j = 0; j < 4; ++j) acc[i][j] = zero4;

  gemm_mainloop(A, W, As, Bs, tm, tn, w, lane, acc);

  const float scale = z ? 1.0f : 0.18033688011112042f;   // Q: 0.125*log2(e)
  u16* C = z ? kh : qh;
#pragma unroll
  for (int rt = 0; rt < 4; ++rt)
#pragma unroll
    for (int nt = 0; nt < 4; ++nt) {
      int row0 = tm + wr + rt * 16 + l4 * 4;
      int col = tn + wc + nt * 16 + l15;
      u16 vb[4];
#pragma unroll
      for (int r = 0; r < 4; ++r) vb[r] = f2bf(acc[rt][nt][r] * scale);
#pragma unroll
      for (int r = 0; r < 4; ++r)
        C[(size_t)(row0 + r) * N + col] = vb[r];
      if (z) {
        int b = row0 >> 11, t = row0 & 2047;
        int h = col >> 6, d = col & 63;
        u16x4 pack = {vb[0], vb[1], vb[2], vb[3]};
        *(u16x4*)&khT[(((size_t)(b * 16 + h) * 64 + d) << 11) + t] = pack;
      }
    }
}

// ---------------- O projection, f32 out ----------------
__global__ __launch_bounds__(256) void gemm_o(
    const u16* __restrict__ A, const u16* __restrict__ W, float* __restrict__ out)
{
  __shared__ __align__(16) u16 As[2 * 4096];
  __shared__ __align__(16) u16 Bs[2 * 4096];
  const int tid = threadIdx.x, w = tid >> 6, lane = tid & 63;
  const int l15 = lane & 15, l4 = lane >> 4;
  const int tm = blockIdx.y * 128, tn = blockIdx.x * 128;
  const int wr = (w >> 1) * 64, wc = (w & 1) * 64;
  const int N = 1024;

  f32x4 zero4 = {0.f, 0.f, 0.f, 0.f};
  f32x4 acc[4][4];
  for (int i = 0; i < 4; ++i)
    for (int j = 0; j < 4; ++j) acc[i][j] = zero4;

  gemm_mainloop(A, W, As, Bs, tm, tn, w, lane, acc);

#pragma unroll
  for (int rt = 0; rt < 4; ++rt)
#pragma unroll
    for (int nt = 0; nt < 4; ++nt) {
      int row0 = tm + wr + rt * 16 + l4 * 4;
      int col = tn + wc + nt * 16 + l15;
#pragma unroll
      for (int r = 0; r < 4; ++r)
        out[(size_t)(row0 + r) * N + col] = acc[rt][nt][r];
    }
}

// ---------------- causal flash attention, V = K, deferred-norm, dbuf, 8 waves ----------------
// grid 512 (XCD-swizzled), 512 threads (8 waves) -> 2 blocks/CU = 16 waves/CU.
// Block = paired 128-row Q-tiles (j, 15-j) -> uniform 34 kt-iters; wave owns 16 q-rows.
// Ks/Kt double-buffered (2x8KB each): DMA for kt+1 issued before compute of kt;
// ONE barrier per iter. Deferred-norm softmax: p = 2^s per-lane, l-reduce at end.
__global__ __launch_bounds__(512) void flash_attn(
    const u16* __restrict__ qh, const u16* __restrict__ kh,
    const u16* __restrict__ khT, u16* __restrict__ ao)
{
  const int T = 2048, E = 1024;
  __shared__ __align__(16) u16 Ks[2 * 4096];     // [buf][keys x d] swizzled
  __shared__ __align__(16) u16 Kt[2 * 4096];     // [buf][d x keys] swizzled
  __shared__ __align__(16) u16 Ps[8][16 * 72];   // per-wave P (q x keys), padded

  const int L = blockIdx.x;                      // 0..511
  const int slot = L >> 3;                       // 0..63
  const int bh = (L & 7) * 8 + (slot >> 3);      // 8 bh per XCD
  const int pj = slot & 7;                       // tile-pair index 0..7
  const int b = bh >> 4, h = bh & 15;
  const size_t base = (size_t)b * T * E + (size_t)h * 64;
  const size_t tb = (size_t)bh * 64 * 2048;
  const int tid = threadIdx.x, w = tid >> 6, lane = tid & 63;
  const int l15 = lane & 15, l4 = lane >> 4;
  const int sw8 = (l4 ^ (l15 & 7)) * 8;          // swizzled in-row offset, kc=0
  const int srow = tid >> 3;                     // staging row 0..63
  const int scol = ((tid & 7) ^ (srow & 7)) * 8; // staging logical col
  f32x4 zero4 = {0.f, 0.f, 0.f, 0.f};

#define STAGEK(kt, bf)                                                             \
  {                                                                                \
    int kbase_ = (kt) * 64;                                                        \
    load16_to_lds(kh + base + (size_t)(kbase_ + srow) * E + scol,                  \
                  (char*)(Ks + (bf) * 4096) + w * 1024);                           \
    load16_to_lds(khT + tb + (size_t)srow * 2048 + kbase_ + scol,                  \
                  (char*)(Kt + (bf) * 4096) + w * 1024);                           \
  }

  for (int half = 0; half < 2; ++half) {
    const int tile = half ? (15 - pj) : pj;      // 128-row Q-tile index
    const int qbase = tile * 128;
    const int wq = qbase + w * 16;               // wave's 16 q-rows

    short8 qf[2];
#pragma unroll
    for (int kc = 0; kc < 2; ++kc)
      qf[kc] = *(const short8*)&qh[base + (size_t)(wq + l15) * E + kc * 32 + l4 * 8];

    f32x4 o[4];
    float l_i[4];
#pragma unroll
    for (int r = 0; r < 4; ++r) { o[r] = zero4; l_i[r] = 0.f; }

    const int nkt = tile * 2 + 2;
    STAGEK(0, 0);
    __syncthreads();
    for (int kt = 0; kt < nkt; ++kt) {
      const int kbase = kt * 64;
      if (kt + 1 < nkt) STAGEK(kt + 1, (kt + 1) & 1);
      const u16* KsC = Ks + (kt & 1) * 4096;
      const u16* KtC = Kt + (kt & 1) * 4096;

      // S = Q K^T (16 x 64 per wave)
      f32x4 s[4];
#pragma unroll
      for (int nt = 0; nt < 4; ++nt) {
        s[nt] = zero4;
#pragma unroll
        for (int kc = 0; kc < 2; ++kc) {
          short8 bfr = *(const short8*)&KsC[(nt * 16 + l15) * 64 + (sw8 ^ (kc * 32))];
          s[nt] = __builtin_amdgcn_mfma_f32_16x16x32_bf16(qf[kc], bfr, s[nt], 0, 0, 0);
        }
      }

      // p = 2^s (deferred norm); mask only near diagonal; truncate-to-bf16 into Ps
      if (kbase + 63 > wq) {                     // wave-uniform
#pragma unroll
        for (int nt = 0; nt < 4; ++nt) {
          int key = kbase + nt * 16 + l15;
#pragma unroll
          for (int r = 0; r < 4; ++r) {
            float p = fexp2(s[nt][r]);
            if (key > wq + l4 * 4 + r) p = 0.f;
            l_i[r] += p;
            Ps[w][(l4 * 4 + r) * 72 + nt * 16 + l15] = (u16)(__float_as_uint(p) >> 16);
          }
        }
      } else {
#pragma unroll
        for (int nt = 0; nt < 4; ++nt)
#pragma unroll
          for (int r = 0; r < 4; ++r) {
            float p = fexp2(s[nt][r]);
            l_i[r] += p;
            Ps[w][(l4 * 4 + r) * 72 + nt * 16 + l15] = (u16)(__float_as_uint(p) >> 16);
          }
      }
      // (no barrier: Ps is per-wave)

      // O += P * V  (V = K; B-frags from Kt rows)
#pragma unroll
      for (int kc = 0; kc < 2; ++kc) {
        short8 pf = *(const short8*)&Ps[w][l15 * 72 + kc * 32 + l4 * 8];
#pragma unroll
        for (int dt = 0; dt < 4; ++dt) {
          short8 vfr = *(const short8*)&KtC[(dt * 16 + l15) * 64 + (sw8 ^ (kc * 32))];
          o[dt] = __builtin_amdgcn_mfma_f32_16x16x32_bf16(pf, vfr, o[dt], 0, 0, 0);
        }
      }
      __syncthreads();   // publishes next buffer; protects current buffer reads
    }

    // deferred l-reduction + normalize + store
#pragma unroll
    for (int d = 1; d < 16; d <<= 1)
#pragma unroll
      for (int r = 0; r < 4; ++r) l_i[r] += __shfl_xor(l_i[r], d);
    float inv[4];
#pragma unroll
    for (int r = 0; r < 4; ++r) inv[r] = frcp(l_i[r]);
#pragma unroll
    for (int dt = 0; dt < 4; ++dt)
#pragma unroll
      for (int r = 0; r < 4; ++r) {
        int row = wq + l4 * 4 + r;
        ao[base + (size_t)row * E + dt * 16 + l15] = f2bf(o[dt][r] * inv[r]);
      }
    __syncthreads();   // half boundary: next half restages Ks/Kt buf 0
  }
#undef STAGEK
}

extern "C" void kernel_launch(void* const* d_in, const int* in_sizes, int n_in,
                              void* d_out, int out_size, void* d_ws, size_t ws_size,
                              hipStream_t stream) {
  (void)in_sizes; (void)n_in; (void)out_size; (void)ws_size;
  const float* q  = (const float*)d_in[0];
  const float* k  = (const float*)d_in[1];
  // d_in[2] = v : unused (share_kv=True)
  const float* Wq = (const float*)d_in[3];
  const float* Wk = (const float*)d_in[4];
  const float* Wo = (const float*)d_in[5];
  float* out = (float*)d_out;

  const size_t nBTE = (size_t)4 * 2048 * 1024;   // 8388608
  const size_t nEE  = (size_t)1024 * 1024;

  char* p = (char*)d_ws;
  u16* q_b  = (u16*)p; p += nBTE * 2;
  u16* k_b  = (u16*)p; p += nBTE * 2;
  u16* Wq_b = (u16*)p; p += nEE * 2;
  u16* Wk_b = (u16*)p; p += nEE * 2;
  u16* Wo_b = (u16*)p; p += nEE * 2;
  u16* qh   = (u16*)p; p += nBTE * 2;
  u16* kh   = (u16*)p; p += nBTE * 2;
  u16* khT  = (u16*)p; p += nBTE * 2;
  u16* ao   = q_b;   // alias: q_b dead after Q-GEMM; flash writes ao after that

  cast_qk<<<dim3(nBTE / 1024, 2), 256, 0, stream>>>(q, k, q_b, k_b);
  cast_w<<<dim3(nEE / 1024, 3), 256, 0, stream>>>(Wq, Wk, Wo, Wq_b, Wk_b, Wo_b);

  gemm_qk<<<dim3(8, 64, 2), 256, 0, stream>>>(q_b, Wq_b, k_b, Wk_b, qh, kh, khT);

  flash_attn<<<dim3(512), 512, 0, stream>>>(qh, kh, khT, ao);

  gemm_o<<<dim3(8, 64), 256, 0, stream>>>(ao, Wo_b, out);
}

// Round 6
// 289.921 us; speedup vs baseline: 1.0245x; 1.0245x over previous
//
#include <hip/hip_runtime.h>
#include <cstdint>

// MHA fused: qh = (q@Wq^T)*0.125*log2e, kh = k@Wk^T (+khT transposed copy),
// flash-causal-attn(qh,kh,V=kh) with deferred-normalization softmax, out = ao@Wo^T.
// GEMM grids are XCD-partitioned: each A row-panel is owned by exactly one XCD
// (fetched once) and each XCD's weight panel stays resident in its 4MB L2.
// Round-5 FETCH_SIZE=134MB (vs 36 ideal) came from 8 XCDs re-fetching every
// A-panel; this mapping removes that.
// B=4 T=2048 E=1024 H=16 D=64. v input (d_in[2]) DEAD (share_kv=True).

typedef unsigned short u16;
typedef __attribute__((ext_vector_type(8))) short short8;
typedef __attribute__((ext_vector_type(4))) float f32x4;
typedef __attribute__((ext_vector_type(4))) unsigned short u16x4;

__device__ __forceinline__ u16 f2bf(float x) {
  unsigned int u = __float_as_uint(x);
  u += 0x7fffu + ((u >> 16) & 1u);   // RNE
  return (u16)(u >> 16);
}

__device__ __forceinline__ float fexp2(float x) {
#if __has_builtin(__builtin_amdgcn_exp2f)
  return __builtin_amdgcn_exp2f(x);
#else
  return __expf(x * 0.69314718056f);
#endif
}

__device__ __forceinline__ float frcp(float x) {
#if __has_builtin(__builtin_amdgcn_rcpf)
  return __builtin_amdgcn_rcpf(x);
#else
  return 1.0f / x;
#endif
}

__device__ __forceinline__ void load16_to_lds(const void* g, void* lds_base_uniform) {
  // HW writes LDS at wave-uniform base + lane*16; g is per-lane.
  __builtin_amdgcn_global_load_lds(
      (const __attribute__((address_space(1))) void*)g,
      (__attribute__((address_space(3))) void*)lds_base_uniform,
      16, 0, 0);
}

// ---------------- casts (merged) ----------------
__global__ void cast_qk(const float* __restrict__ q, const float* __restrict__ k,
                        u16* __restrict__ qb, u16* __restrict__ kb) {
  const float* s = blockIdx.y ? k : q;
  u16* d = blockIdx.y ? kb : qb;
  int i = blockIdx.x * 256 + threadIdx.x;
  float4 f = ((const float4*)s)[i];
  uint2 p;
  p.x = (unsigned int)f2bf(f.x) | ((unsigned int)f2bf(f.y) << 16);
  p.y = (unsigned int)f2bf(f.z) | ((unsigned int)f2bf(f.w) << 16);
  ((uint2*)d)[i] = p;
}

__global__ void cast_w(const float* __restrict__ w0, const float* __restrict__ w1,
                       const float* __restrict__ w2, u16* __restrict__ d0,
                       u16* __restrict__ d1, u16* __restrict__ d2) {
  const float* s = blockIdx.y == 0 ? w0 : (blockIdx.y == 1 ? w1 : w2);
  u16* d = blockIdx.y == 0 ? d0 : (blockIdx.y == 1 ? d1 : d2);
  int i = blockIdx.x * 256 + threadIdx.x;
  float4 f = ((const float4*)s)[i];
  uint2 p;
  p.x = (unsigned int)f2bf(f.x) | ((unsigned int)f2bf(f.y) << 16);
  p.y = (unsigned int)f2bf(f.z) | ((unsigned int)f2bf(f.w) << 16);
  ((uint2*)d)[i] = p;
}

// ---------------- GEMM mainloop: C128x128 = A(128xK) * W(128xK)^T ----------------
// BK=32, double-buffered LDS (2x8KB per operand = 32KB total).
// XOR-swizzled 16B chunks: phys chunk (row*4 + c4) holds logical cols
// ((c4 ^ (row&3))*8 ..+7). K=1024 fixed. 4 waves, 2x2 wave grid, 4x4 frags/wave.
// One barrier per iter: prefetch t+1 -> compute t -> barrier.
__device__ __forceinline__ void gemm_mainloop(
    const u16* __restrict__ A, const u16* __restrict__ W,
    u16* As, u16* Bs, int tm, int tn, int w, int lane, f32x4 acc[4][4])
{
  const int K = 1024;
  const int wr = (w >> 1) * 64, wc = (w & 1) * 64;
  const int l15 = lane & 15, l4 = lane >> 4;

#define STAGE(k0, bf)                                                              \
  {                                                                                \
    _Pragma("unroll")                                                              \
    for (int c = 0; c < 2; ++c) {                                                  \
      int ch = (w * 2 + c) * 64 + lane;        /* phys 16B-chunk 0..511 */         \
      int row = ch >> 2;                                                           \
      int col = ((ch & 3) ^ (row & 3)) * 8;                                        \
      load16_to_lds(A + (size_t)(tm + row) * K + (k0) + col,                       \
                    (char*)(As + (bf) * 4096) + (w * 2 + c) * 1024);               \
      load16_to_lds(W + (size_t)(tn + row) * K + (k0) + col,                       \
                    (char*)(Bs + (bf) * 4096) + (w * 2 + c) * 1024);               \
    }                                                                              \
  }

  STAGE(0, 0);
  __syncthreads();
  for (int t = 0; t < 32; ++t) {
    if (t < 31) STAGE((t + 1) << 5, (t + 1) & 1);
    const u16* Ac = As + (t & 1) * 4096;
    const u16* Bc = Bs + (t & 1) * 4096;
    short8 af[4], bfr[4];
#pragma unroll
    for (int tt = 0; tt < 4; ++tt) {
      int ra = wr + tt * 16 + l15, rb = wc + tt * 16 + l15;
      af[tt]  = *(const short8*)&Ac[ra * 32 + ((l4 ^ (ra & 3)) * 8)];
      bfr[tt] = *(const short8*)&Bc[rb * 32 + ((l4 ^ (rb & 3)) * 8)];
    }
#pragma unroll
    for (int rt = 0; rt < 4; ++rt)
#pragma unroll
      for (int nt = 0; nt < 4; ++nt)
        acc[rt][nt] = __builtin_amdgcn_mfma_f32_16x16x32_bf16(af[rt], bfr[nt], acc[rt][nt], 0, 0, 0);
    __syncthreads();   // drains frag ds_reads (all waves) + next buffer's DMA
  }
#undef STAGE
}

// ---------------- Q + K projections, one XCD-partitioned dispatch ----------------
// grid 1024 1-D. xcd = L&7 (round-robin block->XCD). Even XCDs: Q-proj; odd: K-proj
// -> each XCD touches exactly one 2MB weight matrix (stays L2-resident).
// (m,z) pairs partitioned across XCDs -> each A-panel fetched from HBM once.
__global__ __launch_bounds__(256) void gemm_qk(
    const u16* __restrict__ qb, const u16* __restrict__ Wq,
    const u16* __restrict__ kb, const u16* __restrict__ Wk,
    u16* __restrict__ qh, u16* __restrict__ kh, u16* __restrict__ khT)
{
  __shared__ __align__(16) u16 As[2 * 4096];
  __shared__ __align__(16) u16 Bs[2 * 4096];
  const int L = blockIdx.x;                      // 0..1023
  const int xcd = L & 7;
  const int idx = L >> 3;                        // 0..127
  const int n_tile = idx & 7;
  const int mz = xcd + ((idx >> 3) << 3);        // 0..127: (m,z) pair, unique per XCD
  const int z = mz & 1;                          // = xcd&1: weight fixed per XCD
  const int m_tile = mz >> 1;                    // 0..63

  const u16* A = z ? kb : qb;
  const u16* W = z ? Wk : Wq;
  const int tid = threadIdx.x, w = tid >> 6, lane = tid & 63;
  const int l15 = lane & 15, l4 = lane >> 4;
  const int tm = m_tile * 128, tn = n_tile * 128;
  const int wr = (w >> 1) * 64, wc = (w & 1) * 64;
  const int N = 1024;

  f32x4 zero4 = {0.f, 0.f, 0.f, 0.f};
  f32x4 acc[4][4];
  for (int i = 0; i < 4; ++i)
    for (int j = 0; j < 4; ++j) acc[i][j] = zero4;

  gemm_mainloop(A, W, As, Bs, tm, tn, w, lane, acc);

  const float scale = z ? 1.0f : 0.18033688011112042f;   // Q: 0.125*log2(e)
  u16* C = z ? kh : qh;
#pragma unroll
  for (int rt = 0; rt < 4; ++rt)
#pragma unroll
    for (int nt = 0; nt < 4; ++nt) {
      int row0 = tm + wr + rt * 16 + l4 * 4;
      int col = tn + wc + nt * 16 + l15;
      u16 vb[4];
#pragma unroll
      for (int r = 0; r < 4; ++r) vb[r] = f2bf(acc[rt][nt][r] * scale);
#pragma unroll
      for (int r = 0; r < 4; ++r)
        C[(size_t)(row0 + r) * N + col] = vb[r];
      if (z) {
        int b = row0 >> 11, t = row0 & 2047;
        int h = col >> 6, d = col & 63;
        u16x4 pack = {vb[0], vb[1], vb[2], vb[3]};
        *(u16x4*)&khT[(((size_t)(b * 16 + h) * 64 + d) << 11) + t] = pack;
      }
    }
}

// ---------------- O projection, f32 out, XCD-partitioned ----------------
// grid 512 1-D: m-tile ≡ xcd (mod 8) -> each ao-panel fetched once; Wo L2-resident.
__global__ __launch_bounds__(256) void gemm_o(
    const u16* __restrict__ A, const u16* __restrict__ W, float* __restrict__ out)
{
  __shared__ __align__(16) u16 As[2 * 4096];
  __shared__ __align__(16) u16 Bs[2 * 4096];
  const int L = blockIdx.x;                      // 0..511
  const int xcd = L & 7;
  const int idx = L >> 3;                        // 0..63
  const int n_tile = idx & 7;
  const int m_tile = ((idx >> 3) << 3) + xcd;    // 0..63, unique per XCD

  const int tid = threadIdx.x, w = tid >> 6, lane = tid & 63;
  const int l15 = lane & 15, l4 = lane >> 4;
  const int tm = m_tile * 128, tn = n_tile * 128;
  const int wr = (w >> 1) * 64, wc = (w & 1) * 64;
  const int N = 1024;

  f32x4 zero4 = {0.f, 0.f, 0.f, 0.f};
  f32x4 acc[4][4];
  for (int i = 0; i < 4; ++i)
    for (int j = 0; j < 4; ++j) acc[i][j] = zero4;

  gemm_mainloop(A, W, As, Bs, tm, tn, w, lane, acc);

#pragma unroll
  for (int rt = 0; rt < 4; ++rt)
#pragma unroll
    for (int nt = 0; nt < 4; ++nt) {
      int row0 = tm + wr + rt * 16 + l4 * 4;
      int col = tn + wc + nt * 16 + l15;
#pragma unroll
      for (int r = 0; r < 4; ++r)
        out[(size_t)(row0 + r) * N + col] = acc[rt][nt][r];
    }
}

// ---------------- causal flash attention, V = K, deferred-norm, dbuf, 8 waves ----------------
// grid 512 (XCD-swizzled), 512 threads (8 waves) -> 2 blocks/CU = 16 waves/CU.
// Block = paired 128-row Q-tiles (j, 15-j) -> uniform 34 kt-iters; wave owns 16 q-rows.
// Ks/Kt double-buffered (2x8KB each): DMA for kt+1 issued before compute of kt;
// ONE barrier per iter. Deferred-norm softmax: p = 2^s per-lane, l-reduce at end.
__global__ __launch_bounds__(512) void flash_attn(
    const u16* __restrict__ qh, const u16* __restrict__ kh,
    const u16* __restrict__ khT, u16* __restrict__ ao)
{
  const int T = 2048, E = 1024;
  __shared__ __align__(16) u16 Ks[2 * 4096];     // [buf][keys x d] swizzled
  __shared__ __align__(16) u16 Kt[2 * 4096];     // [buf][d x keys] swizzled
  __shared__ __align__(16) u16 Ps[8][16 * 72];   // per-wave P (q x keys), padded

  const int L = blockIdx.x;                      // 0..511
  const int slot = L >> 3;                       // 0..63
  const int bh = (L & 7) * 8 + (slot >> 3);      // 8 bh per XCD
  const int pj = slot & 7;                       // tile-pair index 0..7
  const int b = bh >> 4, h = bh & 15;
  const size_t base = (size_t)b * T * E + (size_t)h * 64;
  const size_t tb = (size_t)bh * 64 * 2048;
  const int tid = threadIdx.x, w = tid >> 6, lane = tid & 63;
  const int l15 = lane & 15, l4 = lane >> 4;
  const int sw8 = (l4 ^ (l15 & 7)) * 8;          // swizzled in-row offset, kc=0
  const int srow = tid >> 3;                     // staging row 0..63
  const int scol = ((tid & 7) ^ (srow & 7)) * 8; // staging logical col
  f32x4 zero4 = {0.f, 0.f, 0.f, 0.f};

#define STAGEK(kt, bf)                                                             \
  {                                                                                \
    int kbase_ = (kt) * 64;                                                        \
    load16_to_lds(kh + base + (size_t)(kbase_ + srow) * E + scol,                  \
                  (char*)(Ks + (bf) * 4096) + w * 1024);                           \
    load16_to_lds(khT + tb + (size_t)srow * 2048 + kbase_ + scol,                  \
                  (char*)(Kt + (bf) * 4096) + w * 1024);                           \
  }

  for (int half = 0; half < 2; ++half) {
    const int tile = half ? (15 - pj) : pj;      // 128-row Q-tile index
    const int qbase = tile * 128;
    const int wq = qbase + w * 16;               // wave's 16 q-rows

    short8 qf[2];
#pragma unroll
    for (int kc = 0; kc < 2; ++kc)
      qf[kc] = *(const short8*)&qh[base + (size_t)(wq + l15) * E + kc * 32 + l4 * 8];

    f32x4 o[4];
    float l_i[4];
#pragma unroll
    for (int r = 0; r < 4; ++r) { o[r] = zero4; l_i[r] = 0.f; }

    const int nkt = tile * 2 + 2;
    STAGEK(0, 0);
    __syncthreads();
    for (int kt = 0; kt < nkt; ++kt) {
      const int kbase = kt * 64;
      if (kt + 1 < nkt) STAGEK(kt + 1, (kt + 1) & 1);
      const u16* KsC = Ks + (kt & 1) * 4096;
      const u16* KtC = Kt + (kt & 1) * 4096;

      // S = Q K^T (16 x 64 per wave)
      f32x4 s[4];
#pragma unroll
      for (int nt = 0; nt < 4; ++nt) {
        s[nt] = zero4;
#pragma unroll
        for (int kc = 0; kc < 2; ++kc) {
          short8 bfr = *(const short8*)&KsC[(nt * 16 + l15) * 64 + (sw8 ^ (kc * 32))];
          s[nt] = __builtin_amdgcn_mfma_f32_16x16x32_bf16(qf[kc], bfr, s[nt], 0, 0, 0);
        }
      }

      // p = 2^s (deferred norm); mask only near diagonal; truncate-to-bf16 into Ps
      if (kbase + 63 > wq) {                     // wave-uniform
#pragma unroll
        for (int nt = 0; nt < 4; ++nt) {
          int key = kbase + nt * 16 + l15;
#pragma unroll
          for (int r = 0; r < 4; ++r) {
            float p = fexp2(s[nt][r]);
            if (key > wq + l4 * 4 + r) p = 0.f;
            l_i[r] += p;
            Ps[w][(l4 * 4 + r) * 72 + nt * 16 + l15] = (u16)(__float_as_uint(p) >> 16);
          }
        }
      } else {
#pragma unroll
        for (int nt = 0; nt < 4; ++nt)
#pragma unroll
          for (int r = 0; r < 4; ++r) {
            float p = fexp2(s[nt][r]);
            l_i[r] += p;
            Ps[w][(l4 * 4 + r) * 72 + nt * 16 + l15] = (u16)(__float_as_uint(p) >> 16);
          }
      }
      // (no barrier: Ps is per-wave)

      // O += P * V  (V = K; B-frags from Kt rows)
#pragma unroll
      for (int kc = 0; kc < 2; ++kc) {
        short8 pf = *(const short8*)&Ps[w][l15 * 72 + kc * 32 + l4 * 8];
#pragma unroll
        for (int dt = 0; dt < 4; ++dt) {
          short8 vfr = *(const short8*)&KtC[(dt * 16 + l15) * 64 + (sw8 ^ (kc * 32))];
          o[dt] = __builtin_amdgcn_mfma_f32_16x16x32_bf16(pf, vfr, o[dt], 0, 0, 0);
        }
      }
      __syncthreads();   // publishes next buffer; protects current buffer reads
    }

    // deferred l-reduction + normalize + store
#pragma unroll
    for (int d = 1; d < 16; d <<= 1)
#pragma unroll
      for (int r = 0; r < 4; ++r) l_i[r] += __shfl_xor(l_i[r], d);
    float inv[4];
#pragma unroll
    for (int r = 0; r < 4; ++r) inv[r] = frcp(l_i[r]);
#pragma unroll
    for (int dt = 0; dt < 4; ++dt)
#pragma unroll
      for (int r = 0; r < 4; ++r) {
        int row = wq + l4 * 4 + r;
        ao[base + (size_t)row * E + dt * 16 + l15] = f2bf(o[dt][r] * inv[r]);
      }
    __syncthreads();   // half boundary: next half restages Ks/Kt buf 0
  }
#undef STAGEK
}

extern "C" void kernel_launch(void* const* d_in, const int* in_sizes, int n_in,
                              void* d_out, int out_size, void* d_ws, size_t ws_size,
                              hipStream_t stream) {
  (void)in_sizes; (void)n_in; (void)out_size; (void)ws_size;
  const float* q  = (const float*)d_in[0];
  const float* k  = (const float*)d_in[1];
  // d_in[2] = v : unused (share_kv=True)
  const float* Wq = (const float*)d_in[3];
  const float* Wk = (const float*)d_in[4];
  const float* Wo = (const float*)d_in[5];
  float* out = (float*)d_out;

  const size_t nBTE = (size_t)4 * 2048 * 1024;   // 8388608
  const size_t nEE  = (size_t)1024 * 1024;

  char* p = (char*)d_ws;
  u16* q_b  = (u16*)p; p += nBTE * 2;
  u16* k_b  = (u16*)p; p += nBTE * 2;
  u16* Wq_b = (u16*)p; p += nEE * 2;
  u16* Wk_b = (u16*)p; p += nEE * 2;
  u16* Wo_b = (u16*)p; p += nEE * 2;
  u16* qh   = (u16*)p; p += nBTE * 2;
  u16* kh   = (u16*)p; p += nBTE * 2;
  u16* khT  = (u16*)p; p += nBTE * 2;
  u16* ao   = q_b;   // alias: q_b dead after Q-GEMM; flash writes ao after that

  cast_qk<<<dim3(nBTE / 1024, 2), 256, 0, stream>>>(q, k, q_b, k_b);
  cast_w<<<dim3(nEE / 1024, 3), 256, 0, stream>>>(Wq, Wk, Wo, Wq_b, Wk_b, Wo_b);

  gemm_qk<<<dim3(1024), 256, 0, stream>>>(q_b, Wq_b, k_b, Wk_b, qh, kh, khT);

  flash_attn<<<dim3(512), 512, 0, stream>>>(qh, kh, khT, ao);

  gemm_o<<<dim3(512), 256, 0, stream>>>(ao, Wo_b, out);
}